// Round 6
// baseline (292.966 us; speedup 1.0000x reference)
//
#include <hip/hip_runtime.h>
#include <math.h>

#define D_MODEL 1024
#define D_FF    4096
#define RANK    128
#define M_ROWS  8192

typedef _Float16 f16;
typedef _Float16 f16x8 __attribute__((ext_vector_type(8)));
typedef float    f32x4 __attribute__((ext_vector_type(4)));

#define MFMA16(a, b, c) __builtin_amdgcn_mfma_f32_16x16x32_f16((a), (b), (c), 0, 0, 0)

__device__ __forceinline__ f16x8 ld8(const f16* p) { return *(const f16x8*)p; }

__device__ __forceinline__ float gelu_exact(float v) {
    return 0.5f * v * (1.0f + erff(v * 0.70710678118654752440f));
}

// ---------------------------------------------------------------------------
// Prep (verbatim R2/R5, proven): convert/transpose/scale weights into ws (f16).
// ---------------------------------------------------------------------------
__global__ __launch_bounds__(256) void k_prep(
    const float* __restrict__ cfcU, const float* __restrict__ cfcS,
    const float* __restrict__ cfcV, const float* __restrict__ pjU,
    const float* __restrict__ pjS,  const float* __restrict__ pjV,
    f16* __restrict__ w1T, f16* __restrict__ v1,
    f16* __restrict__ w2T, f16* __restrict__ v2)
{
    int i = blockIdx.x * 256 + threadIdx.x;
    if (i < 131072) {
        int r = i >> 10, d = i & 1023;
        w1T[i] = (f16)(cfcU[d * RANK + r] * cfcS[r]);
    } else if (i < 655360) {
        int j = i - 131072;
        v1[j] = (f16)cfcV[j];
    } else if (i < 1179648) {
        int j = i - 655360;
        int r = j >> 12, f = j & 4095;
        w2T[j] = (f16)(pjU[f * RANK + r] * pjS[r]);
    } else if (i < 1310720) {
        int j = i - 1179648;
        v2[j] = (f16)pjV[j];
    }
}

// ---------------------------------------------------------------------------
// Stage 1: t1[m][r] = x[m][:] @ w1T[r][:]^T, f16 out.
// R6: n-split for occupancy. 1 wave (64 thr) per block; wave = 16m x 32n over
// full K=1024. Grid (512 m-tiles, 4 n-splits) -> 2048 waves = 2/SIMD.
// No reduction, no cross-wave communication (same math as proven R5, fewer
// n-tiles per wave). x read 4x (L3-resident, 134 MB).
// ---------------------------------------------------------------------------
__global__ __launch_bounds__(64) void k_t1(
    const float* __restrict__ x, const f16* __restrict__ w1T,
    f16* __restrict__ t1)
{
    const int lane = threadIdx.x & 63;
    const int m0   = blockIdx.x * 16;
    const int n0   = blockIdx.y * 32;
    const int c    = lane & 15, q = lane >> 4;

    f32x4 acc[2] = {};
    const float* xrow = x + (size_t)(m0 + c) * D_MODEL;

#pragma unroll 4
    for (int kb = 0; kb < 32; ++kb) {
        const float* ap = xrow + kb * 32 + q * 8;
        float4 a0 = *(const float4*)ap;
        float4 a1 = *(const float4*)(ap + 4);
        f16x8 af = { (f16)a0.x, (f16)a0.y, (f16)a0.z, (f16)a0.w,
                     (f16)a1.x, (f16)a1.y, (f16)a1.z, (f16)a1.w };
#pragma unroll
        for (int nt = 0; nt < 2; ++nt) {
            f16x8 bf = ld8(w1T + (size_t)(n0 + nt * 16 + c) * D_MODEL + kb * 32 + q * 8);
            acc[nt] = MFMA16(af, bf, acc[nt]);
        }
    }
#pragma unroll
    for (int nt = 0; nt < 2; ++nt)
#pragma unroll
        for (int i2 = 0; i2 < 4; ++i2)
            t1[(size_t)(m0 + q * 4 + i2) * RANK + n0 + nt * 16 + c] = (f16)acc[nt][i2];
}

#define RED_STORE(buf, acc)                                            \
    _Pragma("unroll") for (int rt = 0; rt < 8; ++rt)                   \
    _Pragma("unroll") for (int i2 = 0; i2 < 4; ++i2)                   \
        (buf)[q * 4 + i2][rt * 16 + c] = (acc)[rt][i2];
#define RED_ADD(buf, acc)                                              \
    _Pragma("unroll") for (int rt = 0; rt < 8; ++rt)                   \
    _Pragma("unroll") for (int i2 = 0; i2 < 4; ++i2)                   \
        (acc)[rt][i2] += (buf)[q * 4 + i2][rt * 16 + c];

// ---------------------------------------------------------------------------
// Fused stages 2+3. R5 body + software pipeline:
//  - bf2 (v1 frags) for chunk ch+1 are loaded in SOURCE ORDER before the asm
//    barrier (the "memory" clobber can't reorder them, but honors placement),
//    overwriting bf2 right after its last MFMA use -> loads fly across the
//    barrier via vmcnt while gelu + stage 3 execute.
//  - hs double-buffered by chunk parity -> tail barrier removed (write(i+1)
//    goes to the other parity; the per-iter barrier still orders read(i,p)
//    vs write(i+2,p)).
// 2-wave reduce epilogue: verbatim R5 (proven). Grid (512,2) x 2 waves.
// ---------------------------------------------------------------------------
__global__ __launch_bounds__(128, 2) void k_fused(
    const f16* __restrict__ t1, const f16* __restrict__ v1,
    const float* __restrict__ bfc, const f16* __restrict__ w2T,
    f16* __restrict__ t2p)
{
    __shared__ __align__(16) f16 hs[2][2][16][72];   // [wave][parity][m][f]
    __shared__ float red[16][132];

    const int lane = threadIdx.x & 63;
    const int wv   = threadIdx.x >> 6;
    const int m0   = blockIdx.x * 16;
    const int s    = blockIdx.y;
    const int c    = lane & 15, q = lane >> 4;

    // A2 fragments (t1 rows) — live in regs across the whole f-loop
    f16x8 a2[4];
#pragma unroll
    for (int kb = 0; kb < 4; ++kb)
        a2[kb] = ld8(t1 + (size_t)(m0 + c) * RANK + kb * 32 + q * 8);

    f32x4 c3[8] = {};

    // prefetch chunk 0's v1 fragments
    f16x8 bf2[4][4];
    {
        const int f0 = s * 2048 + (wv * 16) * 64;
#pragma unroll
        for (int nt = 0; nt < 4; ++nt)
#pragma unroll
            for (int kb = 0; kb < 4; ++kb)
                bf2[nt][kb] = ld8(v1 + (size_t)(f0 + nt * 16 + c) * RANK + kb * 32 + q * 8);
    }

#pragma unroll 1
    for (int ch = 0; ch < 16; ++ch) {
        const int f0 = s * 2048 + (wv * 16 + ch) * 64;
        const int fn = s * 2048 + (wv * 16 + ((ch + 1) & 15)) * 64;  // wrap: reload ch0 (harmless)

        // ---- stage 2: 16 MFMAs on current bf2
        f32x4 c2[4] = {};
#pragma unroll
        for (int nt = 0; nt < 4; ++nt)
#pragma unroll
            for (int kb = 0; kb < 4; ++kb)
                c2[nt] = MFMA16(a2[kb], bf2[nt][kb], c2[nt]);

        // ---- current chunk's stage-3 B frags (in flight across gelu+barrier)
        f16x8 bf3[2][8];
#pragma unroll
        for (int kb2 = 0; kb2 < 2; ++kb2)
#pragma unroll
            for (int rt = 0; rt < 8; ++rt)
                bf3[kb2][rt] = ld8(w2T + (size_t)(rt * 16 + c) * D_FF + f0 + kb2 * 32 + q * 8);

        // ---- prefetch NEXT chunk's v1 frags (bf2 dead after stage-2 MFMAs)
#pragma unroll
        for (int nt = 0; nt < 4; ++nt)
#pragma unroll
            for (int kb = 0; kb < 4; ++kb)
                bf2[nt][kb] = ld8(v1 + (size_t)(fn + nt * 16 + c) * RANK + kb * 32 + q * 8);

        // ---- bias + exact gelu -> hs[wv][parity] (C-layout scatter)
#pragma unroll
        for (int nt = 0; nt < 4; ++nt) {
            float b = bfc[f0 + nt * 16 + c];
#pragma unroll
            for (int i2 = 0; i2 < 4; ++i2)
                hs[wv][ch & 1][q * 4 + i2][nt * 16 + c] = (f16)gelu_exact(c2[nt][i2] + b);
        }
        // cross-lane RAW inside the wave: compiler barrier + drain DS queue
        asm volatile("s_waitcnt lgkmcnt(0)" ::: "memory");

        // ---- stage 3: t2 += h @ w2T^T  (A from LDS in A-layout)
#pragma unroll
        for (int kb2 = 0; kb2 < 2; ++kb2) {
            f16x8 a3 = *(const f16x8*)&hs[wv][ch & 1][c][kb2 * 32 + q * 8];
#pragma unroll
            for (int rt = 0; rt < 8; ++rt)
                c3[rt] = MFMA16(a3, bf3[kb2][rt], c3[rt]);
        }
        // no tail barrier: next iteration writes the other hs parity
    }

    // ---- minimal 2-wave reduce (verbatim R5, proven)
    if (wv == 1) { RED_STORE(red, c3) }
    __syncthreads();
    if (wv == 0) {
        RED_ADD(red, c3)
        f16* o = t2p + (size_t)s * (M_ROWS * RANK);
#pragma unroll
        for (int rt = 0; rt < 8; ++rt)
#pragma unroll
            for (int i2 = 0; i2 < 4; ++i2)
                o[(size_t)(m0 + q * 4 + i2) * RANK + rt * 16 + c] = (f16)c3[rt][i2];
    }
}

// ---------------------------------------------------------------------------
// Stage 4: out = (t2p0+t2p1) @ v2^T + bpj, fp32 out.
// R6: wave tile 16m x 128n (nt<8), grid (128, 8) -> 4096 waves = 4/SIMD.
// Body otherwise verbatim R5.
// ---------------------------------------------------------------------------
__global__ __launch_bounds__(256) void k_out(
    const f16* __restrict__ t2p, const f16* __restrict__ v2,
    const float* __restrict__ bpj, float* __restrict__ out)
{
    const int lane = threadIdx.x & 63;
    const int wv   = threadIdx.x >> 6;
    const int m0   = blockIdx.x * 64 + wv * 16;
    const int n0   = blockIdx.y * 128;
    const int c    = lane & 15, q = lane >> 4;

    f16x8 a[4];
#pragma unroll
    for (int kb = 0; kb < 4; ++kb) {
        const size_t off = (size_t)(m0 + c) * RANK + kb * 32 + q * 8;
        f16x8 p0 = ld8(t2p + off);
        f16x8 p1 = ld8(t2p + (size_t)(M_ROWS * RANK) + off);
#pragma unroll
        for (int e = 0; e < 8; ++e)
            a[kb][e] = (f16)((float)p0[e] + (float)p1[e]);
    }

    f32x4 acc[8] = {};
#pragma unroll
    for (int nt = 0; nt < 8; ++nt)
#pragma unroll
        for (int kb = 0; kb < 4; ++kb) {
            f16x8 bf = ld8(v2 + (size_t)(n0 + nt * 16 + c) * RANK + kb * 32 + q * 8);
            acc[nt] = MFMA16(a[kb], bf, acc[nt]);
        }

#pragma unroll
    for (int nt = 0; nt < 8; ++nt) {
        float b = bpj[n0 + nt * 16 + c];
#pragma unroll
        for (int i2 = 0; i2 < 4; ++i2)
            out[(size_t)(m0 + q * 4 + i2) * D_MODEL + n0 + nt * 16 + c] =
                acc[nt][i2] + b;
    }
}

extern "C" void kernel_launch(void* const* d_in, const int* in_sizes, int n_in,
                              void* d_out, int out_size, void* d_ws, size_t ws_size,
                              hipStream_t stream) {
    const float* x    = (const float*)d_in[0];
    const float* cfcU = (const float*)d_in[1];
    const float* cfcS = (const float*)d_in[2];
    const float* cfcV = (const float*)d_in[3];
    const float* cfcB = (const float*)d_in[4];
    const float* pjU  = (const float*)d_in[5];
    const float* pjS  = (const float*)d_in[6];
    const float* pjV  = (const float*)d_in[7];
    const float* pjB  = (const float*)d_in[8];
    float* out = (float*)d_out;

    // ws layout (f16 elements), verbatim R5 (proven), ~8.9 MB total:
    f16* wsf = (f16*)d_ws;
    f16* t1  = wsf;                 // [8192*128]
    f16* t2p = wsf + 1048576;       // [2][8192*128]
    f16* w1T = wsf + 3145728;       // [128*1024]
    f16* v1  = wsf + 3276800;       // [4096*128]
    f16* w2T = wsf + 3801088;       // [128*4096]
    f16* v2  = wsf + 4325376;       // [1024*128]

    k_prep <<<dim3(5120), 256, 0, stream>>>(cfcU, cfcS, cfcV, pjU, pjS, pjV,
                                            w1T, v1, w2T, v2);
    k_t1   <<<dim3(M_ROWS / 16, 4), 64, 0, stream>>>(x, w1T, t1);
    k_fused<<<dim3(M_ROWS / 16, 2), 128, 0, stream>>>(t1, v1, cfcB, w2T, t2p);
    k_out  <<<dim3(M_ROWS / 64, D_MODEL / 128), 256, 0, stream>>>(t2p, v2, pjB, out);
}